// Round 1
// baseline (267.993 us; speedup 1.0000x reference)
//
#include <hip/hip_runtime.h>
#include <math.h>

#define NPTS 16384
#define DIM  24
#define ESIG 65536
#define ERND 32768

// ws layout (floats):
//   [0 .. 16383]      sq[i] = ||emb_i||^2
//   [16384 .. +255]   signal partials (256 blocks)
//   [16640 .. +127]   random partials (128 blocks)
//   [16768 .. +511]   knn partials    (512 blocks)

__device__ __forceinline__ float wave_reduce(float v) {
#pragma unroll
    for (int off = 32; off > 0; off >>= 1)
        v += __shfl_down(v, off, 64);
    return v;
}

// all threads call; thread 0 stores the block sum to *slot
__device__ __forceinline__ void block_reduce_store(float v, float* slot) {
    __shared__ float red[8];
    int lane = threadIdx.x & 63;
    int wid  = threadIdx.x >> 6;
    v = wave_reduce(v);
    if (lane == 0) red[wid] = v;
    __syncthreads();
    if (threadIdx.x == 0) {
        float s = 0.f;
        int nw = blockDim.x >> 6;
        for (int w = 0; w < nw; ++w) s += red[w];
        *slot = s;
    }
}

__global__ void sq_kernel(const float* __restrict__ emb, float* __restrict__ sq) {
    int i = blockIdx.x * blockDim.x + threadIdx.x;
    if (i < NPTS) {
        const float4* row = reinterpret_cast<const float4*>(emb + i * DIM);
        float s = 0.f;
#pragma unroll
        for (int k = 0; k < 6; ++k) {
            float4 v = row[k];
            s += v.x * v.x + v.y * v.y + v.z * v.z + v.w * v.w;
        }
        sq[i] = s;
    }
}

// signal: sum over edges of (||a-b||^2 + 1e-12)
__global__ void edge_signal_kernel(const float* __restrict__ emb,
                                   const int* __restrict__ edges,
                                   float* __restrict__ partial) {
    int e = blockIdx.x * 256 + threadIdx.x;
    int a = edges[e];
    int b = edges[ESIG + e];
    const float4* ra = reinterpret_cast<const float4*>(emb + a * DIM);
    const float4* rb = reinterpret_cast<const float4*>(emb + b * DIM);
    float d2 = 1e-12f;
#pragma unroll
    for (int k = 0; k < 6; ++k) {
        float4 va = ra[k], vb = rb[k];
        float dx = va.x - vb.x, dy = va.y - vb.y;
        float dz = va.z - vb.z, dw = va.w - vb.w;
        d2 += dx * dx; d2 += dy * dy; d2 += dz * dz; d2 += dw * dw;
    }
    block_reduce_store(d2, &partial[blockIdx.x]);
}

// random: sum over edges with pid[a]!=pid[b] of relu(1-d)^2
__global__ void edge_rand_kernel(const float* __restrict__ emb,
                                 const int* __restrict__ edges,
                                 const int* __restrict__ pid,
                                 float* __restrict__ partial) {
    int e = blockIdx.x * 256 + threadIdx.x;
    int a = edges[e];
    int b = edges[ERND + e];
    float v = 0.f;
    if (pid[a] != pid[b]) {
        const float4* ra = reinterpret_cast<const float4*>(emb + a * DIM);
        const float4* rb = reinterpret_cast<const float4*>(emb + b * DIM);
        float d2 = 1e-12f;
#pragma unroll
        for (int k = 0; k < 6; ++k) {
            float4 va = ra[k], vb = rb[k];
            float dx = va.x - vb.x, dy = va.y - vb.y;
            float dz = va.z - vb.z, dw = va.w - vb.w;
            d2 += dx * dx; d2 += dy * dy; d2 += dz * dz; d2 += dw * dw;
        }
        float d = sqrtf(d2);
        float h = 1.f - d;
        if (h > 0.f) v = h * h;
    }
    block_reduce_store(v, &partial[blockIdx.x]);
}

// knn: tiled N x N pass. Each thread owns 4 rows (registers); j-tiles of 128
// staged in LDS. Block = 256 threads -> 1024 rows. grid = (16 i-blocks, 32 j-segs).
__global__ __launch_bounds__(256) void knn_kernel(const float* __restrict__ emb,
                                                  const float* __restrict__ sq,
                                                  const int* __restrict__ pid,
                                                  float* __restrict__ partial) {
    const int t  = threadIdx.x;
    const int ib = blockIdx.x;   // 16 -> rows ib*1024 .. +1023
    const int jb = blockIdx.y;   // 32 -> cols jb*512 .. +511
    const int i0 = ib * 1024 + t * 4;

    float4 a[4][6];
    float  sa[4];
    int    pa[4];
#pragma unroll
    for (int r = 0; r < 4; ++r) {
        const float4* rowp = reinterpret_cast<const float4*>(emb + (size_t)(i0 + r) * DIM);
#pragma unroll
        for (int k = 0; k < 6; ++k) a[r][k] = rowp[k];
        sa[r] = sq[i0 + r];
        pa[r] = pid[i0 + r];
    }

    __shared__ float4 jt[128 * 6];
    __shared__ float  sj[128];
    __shared__ int    pj[128];

    float acc = 0.f;

    for (int tile = 0; tile < 4; ++tile) {
        int j0 = jb * 512 + tile * 128;
        __syncthreads();
        // stage 128 rows x 24 floats = 768 float4, 3 per thread (coalesced)
        const float4* g = reinterpret_cast<const float4*>(emb) + (size_t)j0 * 6;
        jt[t]       = g[t];
        jt[t + 256] = g[t + 256];
        jt[t + 512] = g[t + 512];
        if (t < 128) { sj[t] = sq[j0 + t]; pj[t] = pid[j0 + t]; }
        __syncthreads();

        for (int jj = 0; jj < 128; ++jj) {
            float4 b0 = jt[jj * 6 + 0], b1 = jt[jj * 6 + 1], b2 = jt[jj * 6 + 2];
            float4 b3 = jt[jj * 6 + 3], b4 = jt[jj * 6 + 4], b5 = jt[jj * 6 + 5];
            float sjv = sj[jj];
            int   pjv = pj[jj];
            int   j   = j0 + jj;

            float d2r[4];
#pragma unroll
            for (int r = 0; r < 4; ++r) {
                float dot = 0.f;
                dot = fmaf(a[r][0].x, b0.x, dot); dot = fmaf(a[r][0].y, b0.y, dot);
                dot = fmaf(a[r][0].z, b0.z, dot); dot = fmaf(a[r][0].w, b0.w, dot);
                dot = fmaf(a[r][1].x, b1.x, dot); dot = fmaf(a[r][1].y, b1.y, dot);
                dot = fmaf(a[r][1].z, b1.z, dot); dot = fmaf(a[r][1].w, b1.w, dot);
                dot = fmaf(a[r][2].x, b2.x, dot); dot = fmaf(a[r][2].y, b2.y, dot);
                dot = fmaf(a[r][2].z, b2.z, dot); dot = fmaf(a[r][2].w, b2.w, dot);
                dot = fmaf(a[r][3].x, b3.x, dot); dot = fmaf(a[r][3].y, b3.y, dot);
                dot = fmaf(a[r][3].z, b3.z, dot); dot = fmaf(a[r][3].w, b3.w, dot);
                dot = fmaf(a[r][4].x, b4.x, dot); dot = fmaf(a[r][4].y, b4.y, dot);
                dot = fmaf(a[r][4].z, b4.z, dot); dot = fmaf(a[r][4].w, b4.w, dot);
                dot = fmaf(a[r][5].x, b5.x, dot); dot = fmaf(a[r][5].y, b5.y, dot);
                dot = fmaf(a[r][5].z, b5.z, dot); dot = fmaf(a[r][5].w, b5.w, dot);
                d2r[r] = sa[r] + sjv - 2.f * dot;
            }

            // hinge nonzero iff d^2 < 1 (MARGIN == R_MAX == 1); essentially never
            if (d2r[0] < 1.f || d2r[1] < 1.f || d2r[2] < 1.f || d2r[3] < 1.f) {
#pragma unroll
                for (int r = 0; r < 4; ++r) {
                    int i = i0 + r;
                    if (d2r[r] < 1.f && i != j && pa[r] != pjv) {
                        float d = sqrtf(fmaxf(d2r[r], 0.f) + 1e-12f);
                        float h = 1.f - d;
                        if (h > 0.f) acc += h * h;
                    }
                }
            }
        }
    }

    block_reduce_store(acc, &partial[blockIdx.y * 16 + blockIdx.x]);
}

__global__ void finalize_kernel(const float* __restrict__ sigP,
                                const float* __restrict__ rndP,
                                const float* __restrict__ knnP,
                                float* __restrict__ out) {
    int t = threadIdx.x;  // 512 threads
    float v = knnP[t] * (1.f / NPTS);
    if (t < 256) v += sigP[t] * (1.f / ESIG);
    if (t < 128) v += rndP[t] * (1.f / ERND);
    block_reduce_store(v, out);
}

extern "C" void kernel_launch(void* const* d_in, const int* in_sizes, int n_in,
                              void* d_out, int out_size, void* d_ws, size_t ws_size,
                              hipStream_t stream) {
    const float* emb   = (const float*)d_in[0];
    const int*   sedge = (const int*)d_in[1];
    const int*   redge = (const int*)d_in[2];
    const int*   pid   = (const int*)d_in[3];
    float* out = (float*)d_out;

    float* sq   = (float*)d_ws;       // 16384
    float* sigP = sq + NPTS;          // 256
    float* rndP = sigP + 256;         // 128
    float* knnP = rndP + 128;         // 512

    sq_kernel<<<NPTS / 256, 256, 0, stream>>>(emb, sq);
    edge_signal_kernel<<<ESIG / 256, 256, 0, stream>>>(emb, sedge, sigP);
    edge_rand_kernel<<<ERND / 256, 256, 0, stream>>>(emb, redge, pid, rndP);
    knn_kernel<<<dim3(16, 32), 256, 0, stream>>>(emb, sq, pid, knnP);
    finalize_kernel<<<1, 512, 0, stream>>>(sigP, rndP, knnP, out);
}

// Round 2
// 186.638 us; speedup vs baseline: 1.4359x; 1.4359x over previous
//
#include <hip/hip_runtime.h>
#include <math.h>

#define NPTS 16384
#define DIM  24
#define KPAD 32
#define ESIG 65536
#define ERND 32768
#define THRESH 2.0f
#define LDSS 40   // padded LDS row stride in bf16 units (80 B, 16B-aligned, 2-way banks)

typedef __attribute__((ext_vector_type(8))) short bf16x8;
typedef __attribute__((ext_vector_type(4))) float f32x4;

// ws layout (floats):
//   [0 .. 16383]        sq[i]
//   [16384 .. +255]     signal partials
//   [16640 .. +127]     random partials
//   [16768 .. +16383]   knn partials (128x128 grid)
//   then: Ab (16384x32 bf16), Bb (16384x32 bf16)

__device__ __forceinline__ unsigned short f2bf(float x) {
    unsigned int u = __float_as_uint(x);
    unsigned int r = u + 0x7fffu + ((u >> 16) & 1u);
    return (unsigned short)(r >> 16);
}

__device__ __forceinline__ float wave_reduce(float v) {
#pragma unroll
    for (int off = 32; off > 0; off >>= 1)
        v += __shfl_down(v, off, 64);
    return v;
}

__device__ __forceinline__ void block_reduce_store(float v, float* slot) {
    __shared__ float red[8];
    int lane = threadIdx.x & 63;
    int wid  = threadIdx.x >> 6;
    v = wave_reduce(v);
    if (lane == 0) red[wid] = v;
    __syncthreads();
    if (threadIdx.x == 0) {
        float s = 0.f;
        int nw = blockDim.x >> 6;
        for (int w = 0; w < nw; ++w) s += red[w];
        *slot = s;
    }
}

// per-row: sq, plus augmented bf16 rows:
//   Ab[i] = [-2*E_i (24), sq_i, 1, 0...]   (A operand, i side)
//   Bb[j] = [ E_j  (24), 1, sq_j, 0...]    (B operand, j side)
// => dot(Ab_i, Bb_j) = sq_i + sq_j - 2*E_i.E_j = d^2(i,j)
__global__ void prep_kernel(const float* __restrict__ emb, float* __restrict__ sq,
                            unsigned short* __restrict__ Ab, unsigned short* __restrict__ Bb) {
    int i = blockIdx.x * 256 + threadIdx.x;
    const float4* rp = reinterpret_cast<const float4*>(emb + (size_t)i * DIM);
    float v[24];
    float s = 0.f;
#pragma unroll
    for (int k = 0; k < 6; ++k) {
        float4 q = rp[k];
        v[4*k+0] = q.x; v[4*k+1] = q.y; v[4*k+2] = q.z; v[4*k+3] = q.w;
        s += q.x*q.x + q.y*q.y + q.z*q.z + q.w*q.w;
    }
    sq[i] = s;
    union { unsigned short u[32]; int4 q[4]; } a, b;
#pragma unroll
    for (int k = 0; k < 24; ++k) { a.u[k] = f2bf(-2.f * v[k]); b.u[k] = f2bf(v[k]); }
    a.u[24] = f2bf(s);   a.u[25] = f2bf(1.f);
    b.u[24] = f2bf(1.f); b.u[25] = f2bf(s);
#pragma unroll
    for (int k = 26; k < 32; ++k) { a.u[k] = 0; b.u[k] = 0; }
    int4* pa = reinterpret_cast<int4*>(Ab + (size_t)i * KPAD);
    int4* pb = reinterpret_cast<int4*>(Bb + (size_t)i * KPAD);
#pragma unroll
    for (int k = 0; k < 4; ++k) { pa[k] = a.q[k]; pb[k] = b.q[k]; }
}

__global__ void edge_signal_kernel(const float* __restrict__ emb,
                                   const int* __restrict__ edges,
                                   float* __restrict__ partial) {
    int e = blockIdx.x * 256 + threadIdx.x;
    int a = edges[e];
    int b = edges[ESIG + e];
    const float4* ra = reinterpret_cast<const float4*>(emb + a * DIM);
    const float4* rb = reinterpret_cast<const float4*>(emb + b * DIM);
    float d2 = 1e-12f;
#pragma unroll
    for (int k = 0; k < 6; ++k) {
        float4 va = ra[k], vb = rb[k];
        float dx = va.x - vb.x, dy = va.y - vb.y;
        float dz = va.z - vb.z, dw = va.w - vb.w;
        d2 += dx * dx; d2 += dy * dy; d2 += dz * dz; d2 += dw * dw;
    }
    block_reduce_store(d2, &partial[blockIdx.x]);
}

__global__ void edge_rand_kernel(const float* __restrict__ emb,
                                 const int* __restrict__ edges,
                                 const int* __restrict__ pid,
                                 float* __restrict__ partial) {
    int e = blockIdx.x * 256 + threadIdx.x;
    int a = edges[e];
    int b = edges[ERND + e];
    float v = 0.f;
    if (pid[a] != pid[b]) {
        const float4* ra = reinterpret_cast<const float4*>(emb + a * DIM);
        const float4* rb = reinterpret_cast<const float4*>(emb + b * DIM);
        float d2 = 1e-12f;
#pragma unroll
        for (int k = 0; k < 6; ++k) {
            float4 va = ra[k], vb = rb[k];
            float dx = va.x - vb.x, dy = va.y - vb.y;
            float dz = va.z - vb.z, dw = va.w - vb.w;
            d2 += dx * dx; d2 += dy * dy; d2 += dz * dz; d2 += dw * dw;
        }
        float d = sqrtf(d2);
        float h = 1.f - d;
        if (h > 0.f) v = h * h;
    }
    block_reduce_store(v, &partial[blockIdx.x]);
}

// 128x128 block tile, 4 waves (2x2), each wave a 64x64 quadrant = 16 MFMA tiles.
// Accumulator IS d^2 (augmentation); epilogue = min-tree + conservative threshold,
// exact fp32 recheck of (essentially nonexistent) candidates.
__global__ __launch_bounds__(256) void knn_mfma_kernel(
    const unsigned short* __restrict__ Ab, const unsigned short* __restrict__ Bb,
    const float* __restrict__ emb, const int* __restrict__ pid,
    float* __restrict__ partial)
{
    __shared__ short lA[128 * LDSS];
    __shared__ short lB[128 * LDSS];
    const int t  = threadIdx.x;
    const int i0 = blockIdx.x * 128;
    const int j0 = blockIdx.y * 128;

    // stage both panels: 128 rows x 32 bf16 = 512 x 16B chunks per panel
#pragma unroll
    for (int p = 0; p < 2; ++p) {
        int idx = t + p * 256;
        int row = idx >> 2, q = idx & 3;
        *reinterpret_cast<int4*>(lA + row * LDSS + q * 8) =
            *reinterpret_cast<const int4*>(Ab + (size_t)(i0 + row) * KPAD + q * 8);
        *reinterpret_cast<int4*>(lB + row * LDSS + q * 8) =
            *reinterpret_cast<const int4*>(Bb + (size_t)(j0 + row) * KPAD + q * 8);
    }
    __syncthreads();

    const int wid = t >> 6, lane = t & 63;
    const int wr = wid >> 1, wc = wid & 1;       // 2x2 wave grid
    const int lrow = lane & 15, lk = (lane >> 4) * 8;

    bf16x8 af[4], bfr[4];
#pragma unroll
    for (int r = 0; r < 4; ++r) {
        af[r]  = *reinterpret_cast<const bf16x8*>(lA + (wr * 64 + r * 16 + lrow) * LDSS + lk);
        bfr[r] = *reinterpret_cast<const bf16x8*>(lB + (wc * 64 + r * 16 + lrow) * LDSS + lk);
    }

    f32x4 acc[4][4];
#pragma unroll
    for (int r = 0; r < 4; ++r)
#pragma unroll
        for (int c = 0; c < 4; ++c)
            acc[r][c] = (f32x4){0.f, 0.f, 0.f, 0.f};

#pragma unroll
    for (int r = 0; r < 4; ++r)
#pragma unroll
        for (int c = 0; c < 4; ++c)
            acc[r][c] = __builtin_amdgcn_mfma_f32_16x16x32_bf16(af[r], bfr[c], acc[r][c], 0, 0, 0);

    // min over all 64 d^2 values held by this lane
    float mn = 1e30f;
#pragma unroll
    for (int r = 0; r < 4; ++r)
#pragma unroll
        for (int c = 0; c < 4; ++c) {
            float m0 = fminf(fminf(acc[r][c][0], acc[r][c][1]),
                             fminf(acc[r][c][2], acc[r][c][3]));
            mn = fminf(mn, m0);
        }

    float lacc = 0.f;
    if (mn < THRESH) {   // fires only on diagonal tiles / true hits
#pragma unroll 1
        for (int r = 0; r < 4; ++r)
#pragma unroll 1
            for (int c = 0; c < 4; ++c)
#pragma unroll 1
                for (int e = 0; e < 4; ++e) {
                    if (acc[r][c][e] < THRESH) {
                        // C layout: col = lane&15, row = (lane>>4)*4 + e
                        int i = i0 + wr * 64 + r * 16 + (lane >> 4) * 4 + e;
                        int j = j0 + wc * 64 + c * 16 + (lane & 15);
                        if (i != j && pid[i] != pid[j]) {
                            const float4* ra = reinterpret_cast<const float4*>(emb + (size_t)i * DIM);
                            const float4* rb = reinterpret_cast<const float4*>(emb + (size_t)j * DIM);
                            float d2 = 0.f;
#pragma unroll
                            for (int k = 0; k < 6; ++k) {
                                float4 va = ra[k], vb = rb[k];
                                float dx = va.x - vb.x, dy = va.y - vb.y;
                                float dz = va.z - vb.z, dw = va.w - vb.w;
                                d2 += dx * dx; d2 += dy * dy; d2 += dz * dz; d2 += dw * dw;
                            }
                            float d = sqrtf(fmaxf(d2, 0.f) + 1e-12f);
                            if (d < 1.f) { float h = 1.f - d; lacc += h * h; }
                        }
                    }
                }
    }

    block_reduce_store(lacc, &partial[blockIdx.y * 128 + blockIdx.x]);
}

__global__ void finalize_kernel(const float* __restrict__ sigP,
                                const float* __restrict__ rndP,
                                const float* __restrict__ knnP,
                                float* __restrict__ out) {
    int t = threadIdx.x;  // 256 threads
    float s = 0.f;
#pragma unroll 1
    for (int k = 0; k < 64; ++k) s += knnP[t + 256 * k];
    float v = s * (1.f / NPTS) + sigP[t] * (1.f / ESIG);
    if (t < 128) v += rndP[t] * (1.f / ERND);
    block_reduce_store(v, out);
}

extern "C" void kernel_launch(void* const* d_in, const int* in_sizes, int n_in,
                              void* d_out, int out_size, void* d_ws, size_t ws_size,
                              hipStream_t stream) {
    const float* emb   = (const float*)d_in[0];
    const int*   sedge = (const int*)d_in[1];
    const int*   redge = (const int*)d_in[2];
    const int*   pid   = (const int*)d_in[3];
    float* out = (float*)d_out;

    float* sq   = (float*)d_ws;          // 16384
    float* sigP = sq + NPTS;             // 256
    float* rndP = sigP + 256;            // 128
    float* knnP = rndP + 128;            // 16384
    unsigned short* Ab = (unsigned short*)(knnP + NPTS);   // 16384*32 bf16
    unsigned short* Bb = Ab + (size_t)NPTS * KPAD;         // 16384*32 bf16

    prep_kernel<<<NPTS / 256, 256, 0, stream>>>(emb, sq, Ab, Bb);
    edge_signal_kernel<<<ESIG / 256, 256, 0, stream>>>(emb, sedge, sigP);
    edge_rand_kernel<<<ERND / 256, 256, 0, stream>>>(emb, redge, pid, rndP);
    knn_mfma_kernel<<<dim3(128, 128), 256, 0, stream>>>(Ab, Bb, emb, pid, knnP);
    finalize_kernel<<<1, 256, 0, stream>>>(sigP, rndP, knnP, out);
}

// Round 3
// 37.330 us; speedup vs baseline: 7.1791x; 4.9997x over previous
//
#include <hip/hip_runtime.h>
#include <math.h>

#define NPTS 16384
#define DIM  24
#define KPAD 32
#define ESIG 65536
#define ERND 32768
#define THRESH 2.0f
#define LDSS 40      // padded LDS row stride in shorts (80 B): 2-way banking, free
#define CAP  8192

typedef __attribute__((ext_vector_type(8))) short bf16x8;
typedef __attribute__((ext_vector_type(4))) float f32x4;

// ws layout:
//   float sigP[256]; float rndP[128]; int cnt[4]; int cand[2*CAP];
//   ushort Ab[16384*32]; ushort Bb[16384*32];

__device__ __forceinline__ unsigned short f2bf(float x) {
    unsigned int u = __float_as_uint(x);
    unsigned int r = u + 0x7fffu + ((u >> 16) & 1u);
    return (unsigned short)(r >> 16);
}

__device__ __forceinline__ float wave_reduce(float v) {
#pragma unroll
    for (int off = 32; off > 0; off >>= 1)
        v += __shfl_down(v, off, 64);
    return v;
}

__device__ __forceinline__ void block_reduce_store(float v, float* slot) {
    __shared__ float red[8];
    int lane = threadIdx.x & 63;
    int wid  = threadIdx.x >> 6;
    v = wave_reduce(v);
    if (lane == 0) red[wid] = v;
    __syncthreads();
    if (threadIdx.x == 0) {
        float s = 0.f;
        int nw = blockDim.x >> 6;
        for (int w = 0; w < nw; ++w) s += red[w];
        *slot = s;
    }
}

__device__ __forceinline__ float edge_d2(const float* __restrict__ emb, int a, int b) {
    const float4* ra = reinterpret_cast<const float4*>(emb + (size_t)a * DIM);
    const float4* rb = reinterpret_cast<const float4*>(emb + (size_t)b * DIM);
    float d2 = 0.f;
#pragma unroll
    for (int k = 0; k < 6; ++k) {
        float4 va = ra[k], vb = rb[k];
        float dx = va.x - vb.x, dy = va.y - vb.y;
        float dz = va.z - vb.z, dw = va.w - vb.w;
        d2 += dx * dx; d2 += dy * dy; d2 += dz * dz; d2 += dw * dw;
    }
    return d2;
}

// blocks [0,64): prep Ab/Bb rows; [64,320): signal edges; [320,448): random edges
__global__ __launch_bounds__(256) void fused_pre_kernel(
    const float* __restrict__ emb, const int* __restrict__ sedge,
    const int* __restrict__ redge, const int* __restrict__ pid,
    unsigned short* __restrict__ Ab, unsigned short* __restrict__ Bb,
    float* __restrict__ sigP, float* __restrict__ rndP, int* __restrict__ cnt)
{
    int b = blockIdx.x, t = threadIdx.x;
    if (b < 64) {
        if (b == 0 && t == 0) cnt[0] = 0;
        int i = b * 256 + t;
        const float4* rp = reinterpret_cast<const float4*>(emb + (size_t)i * DIM);
        float v[24];
        float s = 0.f;
#pragma unroll
        for (int k = 0; k < 6; ++k) {
            float4 q = rp[k];
            v[4*k+0] = q.x; v[4*k+1] = q.y; v[4*k+2] = q.z; v[4*k+3] = q.w;
            s += q.x*q.x + q.y*q.y + q.z*q.z + q.w*q.w;
        }
        union { unsigned short u[32]; int4 q[4]; } a, bb;
#pragma unroll
        for (int k = 0; k < 24; ++k) { a.u[k] = f2bf(-2.f * v[k]); bb.u[k] = f2bf(v[k]); }
        a.u[24] = f2bf(s);   a.u[25] = f2bf(1.f);
        bb.u[24] = f2bf(1.f); bb.u[25] = f2bf(s);
#pragma unroll
        for (int k = 26; k < 32; ++k) { a.u[k] = 0; bb.u[k] = 0; }
        int4* pa = reinterpret_cast<int4*>(Ab + (size_t)i * KPAD);
        int4* pb = reinterpret_cast<int4*>(Bb + (size_t)i * KPAD);
#pragma unroll
        for (int k = 0; k < 4; ++k) { pa[k] = a.q[k]; pb[k] = bb.q[k]; }
    } else if (b < 320) {
        int eb = b - 64;
        int e = eb * 256 + t;
        float d2 = edge_d2(emb, sedge[e], sedge[ESIG + e]) + 1e-12f;
        block_reduce_store(d2, &sigP[eb]);
    } else {
        int eb = b - 320;
        int e = eb * 256 + t;
        int a = redge[e], bj = redge[ERND + e];
        float val = 0.f;
        if (pid[a] != pid[bj]) {
            float d = sqrtf(edge_d2(emb, a, bj) + 1e-12f);
            float h = 1.f - d;
            if (h > 0.f) val = h * h;
        }
        block_reduce_store(val, &rndP[eb]);
    }
}

// 256x128 tile per block-iter; 8 waves (4x2), each wave 64x64 = 16 MFMA tiles,
// K=32 in a single MFMA (C = zero). Detector only: append (i,j) candidates.
__global__ __launch_bounds__(512) void knn_mfma_kernel(
    const unsigned short* __restrict__ Ab, const unsigned short* __restrict__ Bb,
    int* __restrict__ cnt, int* __restrict__ cand)
{
    __shared__ short lB[2][128 * LDSS];
    const int t    = threadIdx.x;
    const int wid  = t >> 6, lane = t & 63;
    const int wr   = wid >> 1, wc = wid & 1;     // 4x2 wave grid
    const int i0   = blockIdx.x * 256;
    const int jbase = blockIdx.y * 2048;
    const int lrow = lane & 15, lkb = (lane >> 4) * 8;

    // A fragments: direct global, coalesced (1KB per instruction per wave)
    bf16x8 af[4];
#pragma unroll
    for (int r = 0; r < 4; ++r)
        af[r] = *reinterpret_cast<const bf16x8*>(
            Ab + (size_t)(i0 + wr * 64 + r * 16 + lrow) * KPAD + lkb);

    const int srow = t >> 2, sq4 = t & 3;
    // stage panel 0
    {
        int4 stg = *reinterpret_cast<const int4*>(
            Bb + (size_t)(jbase + srow) * KPAD + sq4 * 8);
        *reinterpret_cast<int4*>(&lB[0][srow * LDSS + sq4 * 8]) = stg;
    }
    __syncthreads();

    const f32x4 zero = {0.f, 0.f, 0.f, 0.f};
    int buf = 0;
#pragma unroll 1
    for (int p = 0; p < 16; ++p) {
        int4 nxt;
        if (p < 15)
            nxt = *reinterpret_cast<const int4*>(
                Bb + (size_t)(jbase + (p + 1) * 128 + srow) * KPAD + sq4 * 8);

        bf16x8 bfr[4];
#pragma unroll
        for (int c = 0; c < 4; ++c)
            bfr[c] = *reinterpret_cast<const bf16x8*>(
                &lB[buf][(wc * 64 + c * 16 + lrow) * LDSS + lkb]);

        f32x4 acc[4][4];
#pragma unroll
        for (int r = 0; r < 4; ++r)
#pragma unroll
            for (int c = 0; c < 4; ++c)
                acc[r][c] = __builtin_amdgcn_mfma_f32_16x16x32_bf16(af[r], bfr[c], zero, 0, 0, 0);

        float mn = 1e30f;
#pragma unroll
        for (int r = 0; r < 4; ++r)
#pragma unroll
            for (int c = 0; c < 4; ++c)
                mn = fminf(fminf(fminf(fminf(acc[r][c][0], acc[r][c][1]),
                                        acc[r][c][2]), acc[r][c][3]), mn);

        if (mn < THRESH) {   // diagonal tiles / true near-pairs only
            int jp = jbase + p * 128;
#pragma unroll
            for (int r = 0; r < 4; ++r)
#pragma unroll
                for (int c = 0; c < 4; ++c)
#pragma unroll
                    for (int e = 0; e < 4; ++e) {
                        if (acc[r][c][e] < THRESH) {
                            int i = i0 + wr * 64 + r * 16 + (lane >> 4) * 4 + e;
                            int j = jp + wc * 64 + c * 16 + (lane & 15);
                            if (i != j) {
                                int slot = atomicAdd(cnt, 1);
                                if (slot < CAP) {
                                    cand[2 * slot]     = i;
                                    cand[2 * slot + 1] = j;
                                }
                            }
                        }
                    }
        }

        if (p < 15)
            *reinterpret_cast<int4*>(&lB[buf ^ 1][srow * LDSS + sq4 * 8]) = nxt;
        __syncthreads();
        buf ^= 1;
    }
}

// exact fp32 recheck of candidates + final reduction
__global__ __launch_bounds__(256) void finalize_kernel(
    const float* __restrict__ emb, const int* __restrict__ pid,
    const int* __restrict__ cnt, const int* __restrict__ cand,
    const float* __restrict__ sigP, const float* __restrict__ rndP,
    float* __restrict__ out)
{
    int t = threadIdx.x;
    int n = cnt[0];
    if (n > CAP) n = CAP;
    float ca = 0.f;
    for (int k = t; k < n; k += 256) {
        int i = cand[2 * k], j = cand[2 * k + 1];
        if (pid[i] != pid[j]) {
            float d = sqrtf(fmaxf(edge_d2(emb, i, j), 0.f) + 1e-12f);
            if (d < 1.f) { float h = 1.f - d; ca += h * h; }
        }
    }
    float v = ca * (1.f / NPTS) + sigP[t] * (1.f / ESIG);
    if (t < 128) v += rndP[t] * (1.f / ERND);
    block_reduce_store(v, out);
}

extern "C" void kernel_launch(void* const* d_in, const int* in_sizes, int n_in,
                              void* d_out, int out_size, void* d_ws, size_t ws_size,
                              hipStream_t stream) {
    const float* emb   = (const float*)d_in[0];
    const int*   sedge = (const int*)d_in[1];
    const int*   redge = (const int*)d_in[2];
    const int*   pid   = (const int*)d_in[3];
    float* out = (float*)d_out;

    float* sigP = (float*)d_ws;                       // 256
    float* rndP = sigP + 256;                         // 128
    int*   cnt  = (int*)(rndP + 128);                 // 4 (padded)
    int*   cand = cnt + 4;                            // 2*CAP
    unsigned short* Ab = (unsigned short*)(cand + 2 * CAP);   // 16384*32
    unsigned short* Bb = Ab + (size_t)NPTS * KPAD;            // 16384*32

    fused_pre_kernel<<<448, 256, 0, stream>>>(emb, sedge, redge, pid, Ab, Bb, sigP, rndP, cnt);
    knn_mfma_kernel<<<dim3(64, 8), 512, 0, stream>>>(Ab, Bb, cnt, cand);
    finalize_kernel<<<1, 256, 0, stream>>>(emb, pid, cnt, cand, sigP, rndP, out);
}

// Round 4
// 28.051 us; speedup vs baseline: 9.5539x; 1.3308x over previous
//
#include <hip/hip_runtime.h>
#include <math.h>

#define NPTS 16384
#define DIM  24
#define KPAD 32
#define ESIG 65536
#define ERND 32768
#define THRESH 2.0f
#define LDSS 36      // 72 B LDS row stride: row-banks walk all 16 even banks -> 2-way max (free)
#define CAP  8192

typedef __attribute__((ext_vector_type(8))) short bf16x8;
typedef __attribute__((ext_vector_type(4))) float f32x4;

// ws layout:
//   float sigP[256]; float rndP[128]; int cnt[4]; int cand[2*CAP];
//   ushort Ab[16384*32]; ushort Bb[16384*32];

__device__ __forceinline__ unsigned short f2bf(float x) {
    unsigned int u = __float_as_uint(x);
    unsigned int r = u + 0x7fffu + ((u >> 16) & 1u);
    return (unsigned short)(r >> 16);
}

__device__ __forceinline__ float min3f(float a, float b, float c) {
    return fminf(fminf(a, b), c);   // fuses to v_min3_f32
}

__device__ __forceinline__ float wave_reduce(float v) {
#pragma unroll
    for (int off = 32; off > 0; off >>= 1)
        v += __shfl_down(v, off, 64);
    return v;
}

__device__ __forceinline__ void block_reduce_store(float v, float* slot) {
    __shared__ float red[8];
    int lane = threadIdx.x & 63;
    int wid  = threadIdx.x >> 6;
    v = wave_reduce(v);
    if (lane == 0) red[wid] = v;
    __syncthreads();
    if (threadIdx.x == 0) {
        float s = 0.f;
        int nw = blockDim.x >> 6;
        for (int w = 0; w < nw; ++w) s += red[w];
        *slot = s;
    }
}

__device__ __forceinline__ float edge_d2(const float* __restrict__ emb, int a, int b) {
    const float4* ra = reinterpret_cast<const float4*>(emb + (size_t)a * DIM);
    const float4* rb = reinterpret_cast<const float4*>(emb + (size_t)b * DIM);
    float d2 = 0.f;
#pragma unroll
    for (int k = 0; k < 6; ++k) {
        float4 va = ra[k], vb = rb[k];
        float dx = va.x - vb.x, dy = va.y - vb.y;
        float dz = va.z - vb.z, dw = va.w - vb.w;
        d2 += dx * dx; d2 += dy * dy; d2 += dz * dz; d2 += dw * dw;
    }
    return d2;
}

// blocks [0,64): prep Ab/Bb rows; [64,320): signal edges; [320,448): random edges
__global__ __launch_bounds__(256) void fused_pre_kernel(
    const float* __restrict__ emb, const int* __restrict__ sedge,
    const int* __restrict__ redge, const int* __restrict__ pid,
    unsigned short* __restrict__ Ab, unsigned short* __restrict__ Bb,
    float* __restrict__ sigP, float* __restrict__ rndP, int* __restrict__ cnt)
{
    int b = blockIdx.x, t = threadIdx.x;
    if (b < 64) {
        if (b == 0 && t == 0) cnt[0] = 0;
        int i = b * 256 + t;
        const float4* rp = reinterpret_cast<const float4*>(emb + (size_t)i * DIM);
        float v[24];
        float s = 0.f;
#pragma unroll
        for (int k = 0; k < 6; ++k) {
            float4 q = rp[k];
            v[4*k+0] = q.x; v[4*k+1] = q.y; v[4*k+2] = q.z; v[4*k+3] = q.w;
            s += q.x*q.x + q.y*q.y + q.z*q.z + q.w*q.w;
        }
        union { unsigned short u[32]; int4 q[4]; } a, bb;
#pragma unroll
        for (int k = 0; k < 24; ++k) { a.u[k] = f2bf(-2.f * v[k]); bb.u[k] = f2bf(v[k]); }
        a.u[24] = f2bf(s);   a.u[25] = f2bf(1.f);
        bb.u[24] = f2bf(1.f); bb.u[25] = f2bf(s);
#pragma unroll
        for (int k = 26; k < 32; ++k) { a.u[k] = 0; bb.u[k] = 0; }
        int4* pa = reinterpret_cast<int4*>(Ab + (size_t)i * KPAD);
        int4* pb = reinterpret_cast<int4*>(Bb + (size_t)i * KPAD);
#pragma unroll
        for (int k = 0; k < 4; ++k) { pa[k] = a.q[k]; pb[k] = bb.q[k]; }
    } else if (b < 320) {
        int eb = b - 64;
        int e = eb * 256 + t;
        float d2 = edge_d2(emb, sedge[e], sedge[ESIG + e]) + 1e-12f;
        block_reduce_store(d2, &sigP[eb]);
    } else {
        int eb = b - 320;
        int e = eb * 256 + t;
        int a = redge[e], bj = redge[ERND + e];
        float val = 0.f;
        if (pid[a] != pid[bj]) {
            float d = sqrtf(edge_d2(emb, a, bj) + 1e-12f);
            float h = 1.f - d;
            if (h > 0.f) val = h * h;
        }
        block_reduce_store(val, &rndP[eb]);
    }
}

// One-shot 256x128 tile per block; 8 waves (4x2), each wave 64x64 = 16 MFMA.
// Upper-triangle blocks only (bj >= 2*bi); emit candidates with i<j (weight 2 later).
__global__ __launch_bounds__(512) void knn_mfma_kernel(
    const unsigned short* __restrict__ Ab, const unsigned short* __restrict__ Bb,
    int* __restrict__ cnt, int* __restrict__ cand)
{
    const int bi = blockIdx.x;          // 64 i-panels of 256 rows
    const int bj = blockIdx.y;          // 128 j-panels of 128 cols
    if (bj < 2 * bi) return;            // no i<j pairs in this block

    __shared__ short lB[128 * LDSS];
    const int t  = threadIdx.x;
    const int i0 = bi * 256, j0 = bj * 128;

    // stage B panel: 128 rows x 64 B, one int4 per thread (coalesced)
    {
        int row = t >> 2, q = t & 3;
        int4 v = *reinterpret_cast<const int4*>(Bb + (size_t)(j0 + row) * KPAD + q * 8);
        *reinterpret_cast<int4*>(&lB[row * LDSS + q * 8]) = v;
    }

    const int wid = t >> 6, lane = t & 63;
    const int wr = wid >> 1, wc = wid & 1;          // 4x2 wave grid
    const int lrow = lane & 15, lkb = (lane >> 4) * 8;

    // A fragments: direct global, 1 KB contiguous per instruction per wave
    bf16x8 af[4];
#pragma unroll
    for (int r = 0; r < 4; ++r)
        af[r] = *reinterpret_cast<const bf16x8*>(
            Ab + (size_t)(i0 + wr * 64 + r * 16 + lrow) * KPAD + lkb);

    __syncthreads();

    bf16x8 bfr[4];
#pragma unroll
    for (int c = 0; c < 4; ++c)
        bfr[c] = *reinterpret_cast<const bf16x8*>(
            &lB[(wc * 64 + c * 16 + lrow) * LDSS + lkb]);

    const f32x4 zero = {0.f, 0.f, 0.f, 0.f};
    f32x4 acc[4][4];
#pragma unroll
    for (int r = 0; r < 4; ++r)
#pragma unroll
        for (int c = 0; c < 4; ++c)
            acc[r][c] = __builtin_amdgcn_mfma_f32_16x16x32_bf16(af[r], bfr[c], zero, 0, 0, 0);

    // min over the 64 d^2 values this lane holds (min3 trees)
    float tm[16];
#pragma unroll
    for (int r = 0; r < 4; ++r)
#pragma unroll
        for (int c = 0; c < 4; ++c)
            tm[r * 4 + c] = fminf(min3f(acc[r][c][0], acc[r][c][1], acc[r][c][2]),
                                  acc[r][c][3]);
    float m0 = min3f(tm[0], tm[1], tm[2]);
    float m1 = min3f(tm[3], tm[4], tm[5]);
    float m2 = min3f(tm[6], tm[7], tm[8]);
    float m3 = min3f(tm[9], tm[10], tm[11]);
    float m4 = min3f(tm[12], tm[13], tm[14]);
    float mn = fminf(min3f(min3f(m0, m1, m2), m3, m4), tm[15]);

    if (mn < THRESH) {   // fires only for diagonal cells / true near-pairs
#pragma unroll
        for (int r = 0; r < 4; ++r)
#pragma unroll
            for (int c = 0; c < 4; ++c)
#pragma unroll
                for (int e = 0; e < 4; ++e) {
                    if (acc[r][c][e] < THRESH) {
                        int i = i0 + wr * 64 + r * 16 + (lane >> 4) * 4 + e;
                        int j = j0 + wc * 64 + c * 16 + (lane & 15);
                        if (i < j) {
                            int slot = atomicAdd(cnt, 1);
                            if (slot < CAP) {
                                cand[2 * slot]     = i;
                                cand[2 * slot + 1] = j;
                            }
                        }
                    }
                }
    }
}

// exact fp32 recheck of candidates (weight 2: i<j only) + final reduction
__global__ __launch_bounds__(256) void finalize_kernel(
    const float* __restrict__ emb, const int* __restrict__ pid,
    const int* __restrict__ cnt, const int* __restrict__ cand,
    const float* __restrict__ sigP, const float* __restrict__ rndP,
    float* __restrict__ out)
{
    int t = threadIdx.x;
    int n = cnt[0];
    if (n > CAP) n = CAP;
    float ca = 0.f;
    for (int k = t; k < n; k += 256) {
        int i = cand[2 * k], j = cand[2 * k + 1];
        if (pid[i] != pid[j]) {
            float d = sqrtf(fmaxf(edge_d2(emb, i, j), 0.f) + 1e-12f);
            if (d < 1.f) { float h = 1.f - d; ca += h * h; }
        }
    }
    float v = ca * (2.f / NPTS) + sigP[t] * (1.f / ESIG);
    if (t < 128) v += rndP[t] * (1.f / ERND);
    block_reduce_store(v, out);
}

extern "C" void kernel_launch(void* const* d_in, const int* in_sizes, int n_in,
                              void* d_out, int out_size, void* d_ws, size_t ws_size,
                              hipStream_t stream) {
    const float* emb   = (const float*)d_in[0];
    const int*   sedge = (const int*)d_in[1];
    const int*   redge = (const int*)d_in[2];
    const int*   pid   = (const int*)d_in[3];
    float* out = (float*)d_out;

    float* sigP = (float*)d_ws;                       // 256
    float* rndP = sigP + 256;                         // 128
    int*   cnt  = (int*)(rndP + 128);                 // 4 (padded)
    int*   cand = cnt + 4;                            // 2*CAP
    unsigned short* Ab = (unsigned short*)(cand + 2 * CAP);   // 16384*32
    unsigned short* Bb = Ab + (size_t)NPTS * KPAD;            // 16384*32

    fused_pre_kernel<<<448, 256, 0, stream>>>(emb, sedge, redge, pid, Ab, Bb, sigP, rndP, cnt);
    knn_mfma_kernel<<<dim3(64, 128), 512, 0, stream>>>(Ab, Bb, cnt, cand);
    finalize_kernel<<<1, 256, 0, stream>>>(emb, pid, cnt, cand, sigP, rndP, out);
}